// Round 6
// baseline (695.114 us; speedup 1.0000x reference)
//
#include <hip/hip_runtime.h>
#include <stdint.h>
#include <stddef.h>

#define DIM   2048
#define NEXP  64
#define NTOK  32768
#define OFF_IDX  (NTOK*NEXP)          // 2097152
#define OFF_TSC  (OFF_IDX + NTOK*2)   // 2162688

typedef __attribute__((ext_vector_type(4))) float f32x4;

// ---------------------------------------------------------------------------
// Transpose W[e][d] -> Wt[d][e]  (512 KB in d_ws). Per-d expert row is
// contiguous -> wave-uniform scalar (s_load) reads in the main kernel.
// ---------------------------------------------------------------------------
__global__ __launch_bounds__(256) void wtrans(const float* __restrict__ W,
                                              float* __restrict__ Wt) {
    int idx = blockIdx.x * 256 + threadIdx.x;   // 0..131071
    int e = idx & 63, d = idx >> 6;
    Wt[idx] = W[e * DIM + d];
}

// ---------------------------------------------------------------------------
// np/BLAS fp32 semantics preserved EXACTLY (passed R3/R4/R5): logit[t][e] is
// one sequential fmaf chain over d = 0..2047 ascending, then + b[e].
// R6 schedule: 1024 thr = 16 waves/block (wave w owns experts [4w,4w+4) for
// the block's 64 tokens, lane = token). LDS double buffer 2x16KB, logits
// overlaid on the same 32KB -> 2 blocks/CU x 16 waves = 32 waves/CU (8/SIMD).
// One barrier per chunk; global prefetch issued before compute, ds_write
// after (T14). W on scalar pipe (uniform s_load_dwordx4 per d).
// ---------------------------------------------------------------------------
__global__ __launch_bounds__(1024, 8) void router_w16(
        const float* __restrict__ X, const float* __restrict__ Wt,
        const float* __restrict__ B, float* __restrict__ out) {
    __shared__ char smem[32768] __attribute__((aligned(16)));  // 2 tiles / ls

    const int tid  = threadIdx.x;
    const int lane = tid & 63;
    const int w    = __builtin_amdgcn_readfirstlane(tid >> 6); // 0..15
    const int e0   = w * 4;
    const int tokb = blockIdx.x * 64;

    // staging map: thread -> (row, 16B-block) of the [64][64] f32 tile
    const int r_st  = tid >> 4;                // 0..63
    const int cb_st = tid & 15;                // 0..15
    const float* g0 = X + (size_t)(tokb + r_st) * DIM + 4 * cb_st;
    const int wr0 = r_st * 256 + ((16 * cb_st) ^ (16 * (r_st & 7)));

    // compute-side read map: lane = token row (same XOR involution)
    const int rb  = lane * 256;
    const int rsw = 16 * (lane & 7);
    const float* wbase = Wt + e0;

    float acc[4];
#pragma unroll
    for (int e = 0; e < 4; e++) acc[e] = 0.0f;

    // prologue: stage chunk 0 into buffer 0
    *(f32x4*)(smem + wr0) = *(const f32x4*)(g0);
    __syncthreads();

#pragma unroll 1
    for (int it = 0; it < 32; ++it) {
        const int kb = it * 64;
        f32x4 sn;
        if (it < 31) sn = *(const f32x4*)(g0 + kb + 64);   // prefetch next

        const char* cur = smem + (it & 1) * 16384 + rb;
#pragma unroll
        for (int cb = 0; cb < 16; ++cb) {
            f32x4 xv = *(const f32x4*)(cur + ((16 * cb) ^ rsw));
#pragma unroll
            for (int j = 0; j < 4; ++j) {
                const float xvj = xv[j];
                const float* wr = wbase + (size_t)(kb + 4 * cb + j) * NEXP;
#pragma unroll
                for (int e = 0; e < 4; e++)
                    acc[e] = fmaf(xvj, wr[e], acc[e]);  // strict in-order chain
            }
        }

        if (it < 31)
            *(f32x4*)(smem + ((it + 1) & 1) * 16384 + wr0) = sn;
        __syncthreads();                                // one barrier per chunk
    }

    // bias (separate fp32 add, matching einsum + b) -> logits overlay in LDS
    float (*ls)[65] = (float (*)[65])smem;              // 16640 B <= 32768
#pragma unroll
    for (int e = 0; e < 4; e++) ls[lane][e0 + e] = acc[e] + B[e0 + e];

    __syncthreads();

    // -------- phase 2: first wave, lane = token (identical to R3/R4/R5) ----
    if (tid < 64) {
        const int t2 = tokb + lane;
        float l[64];
#pragma unroll
        for (int e = 0; e < 64; e++) l[e] = ls[lane][e];

        float m = l[0];
#pragma unroll
        for (int e = 1; e < 64; e++) m = fmaxf(m, l[e]);

        // top-2 on logits, ascending scan, strict > => lowest-index ties
        float v1 = -3.4e38f, v2 = -3.4e38f;
        int   i1 = 0,        i2 = 0;
#pragma unroll
        for (int e = 0; e < 64; e++) {
            float v = l[e];
            if (v > v1)      { v2 = v1; i2 = i1; v1 = v; i1 = e; }
            else if (v > v2) { v2 = v;  i2 = e; }
        }

        float den = 0.0f;
#pragma unroll
        for (int e = 0; e < 64; e++) { l[e] = __expf(l[e] - m); den += l[e]; }
        const float inv = 1.0f / den;

#pragma unroll
        for (int q = 0; q < 16; q++) {
            f32x4 v;
#pragma unroll
            for (int j = 0; j < 4; j++) v[j] = l[q * 4 + j] * inv;
            *(f32x4*)(out + (size_t)t2 * 64 + q * 4) = v;
        }
        out[OFF_IDX + (size_t)t2 * 2 + 0] = (float)i1;
        out[OFF_IDX + (size_t)t2 * 2 + 1] = (float)i2;
        out[OFF_TSC + (size_t)t2 * 2 + 0] = __expf(v1 - m) * inv;
        out[OFF_TSC + (size_t)t2 * 2 + 1] = __expf(v2 - m) * inv;
    }
}

extern "C" void kernel_launch(void* const* d_in, const int* in_sizes, int n_in,
                              void* d_out, int out_size, void* d_ws, size_t ws_size,
                              hipStream_t stream) {
    const float* X = (const float*)d_in[0];   // [4,8192,2048] f32
    const float* W = (const float*)d_in[1];   // [64,2048] f32
    const float* b = (const float*)d_in[2];   // [64] f32
    float* out = (float*)d_out;
    float* Wt  = (float*)d_ws;                // 512 KB needed

    wtrans<<<512, 256, 0, stream>>>(W, Wt);
    router_w16<<<NTOK / 64, 1024, 0, stream>>>(X, Wt, b, out);
}

// Round 7
// 614.560 us; speedup vs baseline: 1.1311x; 1.1311x over previous
//
#include <hip/hip_runtime.h>
#include <stdint.h>
#include <stddef.h>

#define DIM   2048
#define NEXP  64
#define NTOK  32768
#define OFF_IDX  (NTOK*NEXP)          // 2097152
#define OFF_TSC  (OFF_IDX + NTOK*2)   // 2162688

typedef __attribute__((ext_vector_type(4))) float f32x4;

// ---------------------------------------------------------------------------
// Pre-kernel: W[e][d] -> quad layout Wq[dq][e][r] = W[e][dq*4+r]
// (dq in [0,512), e in [0,64), r in [0,4)).  One dwordx4 per lane per d-quad,
// coalesced across lanes (lane = expert).  512 KB in d_ws.
// ---------------------------------------------------------------------------
__global__ __launch_bounds__(256) void wquad(const float* __restrict__ W,
                                             float* __restrict__ Wq) {
    int idx = blockIdx.x * 256 + threadIdx.x;   // 0..131071
    int r  = idx & 3;
    int e  = (idx >> 2) & 63;
    int dq = idx >> 8;
    Wq[idx] = W[e * DIM + dq * 4 + r];
}

// ---------------------------------------------------------------------------
// np/BLAS fp32 semantics preserved EXACTLY (passed R3/R4/R5): logit[t][e] is
// one sequential fmaf chain over d = 0..2047 ascending, then + b[e].
// R7 schedule: lane = EXPERT. 256 thr = 4 waves/block; wave w owns tokens
// [blk*32 + 8w, +8). Per d-quad: 1 coalesced W dwordx4 (per-lane expert
// quad) + 8 broadcast X dwordx4 (one per token) -> 32 FMAs. Everything on
// vmcnt; NO LDS, NO barriers, NO s_load in the hot loop (lgkmcnt conflation
// gone). Softmax/top-2 are wave-shuffle ops over the 64 expert lanes.
// ---------------------------------------------------------------------------
__global__ __launch_bounds__(256, 4) void router_le(
        const float* __restrict__ X, const float* __restrict__ Wq,
        const float* __restrict__ B, float* __restrict__ out) {
    const int tid  = threadIdx.x;
    const int lane = tid & 63;                 // expert id
    const int w    = tid >> 6;                 // 0..3 (kept divergent-typed)
    const int tok0 = blockIdx.x * 32 + w * 8;

    const float* xp[8];
#pragma unroll
    for (int a = 0; a < 8; a++) xp[a] = X + (size_t)(tok0 + a) * DIM;
    const float* wp = Wq + lane * 4;

    float acc[8];
#pragma unroll
    for (int a = 0; a < 8; a++) acc[a] = 0.0f;

#pragma unroll 4
    for (int cb = 0; cb < 512; ++cb) {
        f32x4 wv = *(const f32x4*)(wp + (size_t)cb * 256);
        f32x4 xv[8];
#pragma unroll
        for (int a = 0; a < 8; a++) xv[a] = *(const f32x4*)(xp[a] + cb * 4);
#pragma unroll
        for (int j = 0; j < 4; ++j)
#pragma unroll
            for (int a = 0; a < 8; a++)
                acc[a] = fmaf(xv[a][j], wv[j], acc[a]);  // strict ascending-d chain
    }

    // ---------------- epilogue: bias + softmax + top-2, all in-wave --------
    const float bb = B[lane];

#pragma unroll
    for (int a = 0; a < 8; a++) {
        const int t = tok0 + a;
        const float lg = acc[a] + bb;          // separate bias add (np order)

        // wave max over 64 experts
        float m = lg;
#pragma unroll
        for (int s = 1; s < 64; s <<= 1) m = fmaxf(m, __shfl_xor(m, s, 64));

        const float p = __expf(lg - m);
        float den = p;
#pragma unroll
        for (int s = 1; s < 64; s <<= 1) den += __shfl_xor(den, s, 64);
        const float inv = 1.0f / den;

        out[(size_t)t * 64 + lane] = p * inv;  // coalesced 256B row

        // top-2 butterfly on logits, ties -> lowest index (np semantics)
        float v1 = lg, v2 = -3.4e38f;
        int   i1 = lane, i2 = 127;
#pragma unroll
        for (int s = 1; s < 64; s <<= 1) {
            float ov1 = __shfl_xor(v1, s, 64), ov2 = __shfl_xor(v2, s, 64);
            int   oi1 = __shfl_xor(i1, s, 64), oi2 = __shfl_xor(i2, s, 64);
            bool  aw  = (v1 > ov1) || (v1 == ov1 && i1 < oi1);
            float nv1 = aw ? v1 : ov1;  int ni1 = aw ? i1 : oi1;
            float cv  = aw ? ov1 : v1;  int ci  = aw ? oi1 : i1;
            float sv  = aw ? v2 : ov2;  int si  = aw ? i2 : oi2;
            bool  c2  = (cv > sv) || (cv == sv && ci < si);
            v1 = nv1; i1 = ni1;
            v2 = c2 ? cv : sv; i2 = c2 ? ci : si;
        }
        if (lane == 0) {
            out[OFF_IDX + (size_t)t * 2 + 0] = (float)i1;
            out[OFF_IDX + (size_t)t * 2 + 1] = (float)i2;
            out[OFF_TSC + (size_t)t * 2 + 0] = __expf(v1 - m) * inv;
            out[OFF_TSC + (size_t)t * 2 + 1] = __expf(v2 - m) * inv;
        }
    }
}

extern "C" void kernel_launch(void* const* d_in, const int* in_sizes, int n_in,
                              void* d_out, int out_size, void* d_ws, size_t ws_size,
                              hipStream_t stream) {
    const float* X = (const float*)d_in[0];   // [4,8192,2048] f32
    const float* W = (const float*)d_in[1];   // [64,2048] f32
    const float* b = (const float*)d_in[2];   // [64] f32
    float* out = (float*)d_out;
    float* Wq  = (float*)d_ws;                // 512 KB needed

    wquad<<<512, 256, 0, stream>>>(W, Wq);
    router_le<<<NTOK / 32, 256, 0, stream>>>(X, Wq, b, out);
}

// Round 8
// 129.236 us; speedup vs baseline: 5.3787x; 4.7553x over previous
//
#include <hip/hip_runtime.h>
#include <hip/hip_bf16.h>
#include <stdint.h>
#include <stddef.h>

#define DIM   2048
#define NEXP  64
#define NTOK  32768
#define KF    64                       // 2048/32 k-fragments
#define OFF_IDX  (NTOK*NEXP)           // 2097152
#define OFF_TSC  (OFF_IDX + NTOK*2)    // 2162688
#define TAU   5e-4f

typedef __attribute__((ext_vector_type(8))) short  short8;
typedef __attribute__((ext_vector_type(4))) float  f32x4;

__device__ __forceinline__ unsigned short bf16_rne(float f) {
    unsigned u = __builtin_bit_cast(unsigned, f);
    u += 0x7fffu + ((u >> 16) & 1u);
    return (unsigned short)(u >> 16);
}
__device__ __forceinline__ float bf16_up(unsigned short s) {
    unsigned u = ((unsigned)s) << 16;
    return __builtin_bit_cast(float, u);
}

// ---------------------------------------------------------------------------
// Pre-kernel: split W into 2 bf16 terms (hi/mid) in MFMA B-fragment order.
// short idx = ((((term*KF+kf)*4+nf)*64)+lane)*8 + j  (262144 shorts = 512KB)
//   element = term( W[nf*16+(lane&15)][kf*32+(lane>>4)*8+j] )
// Also zeroes the ambiguous-token counter (runs before router_mfma).
// ---------------------------------------------------------------------------
__global__ __launch_bounds__(256) void wsplit(const float* __restrict__ W,
                                              short* __restrict__ warr,
                                              int* __restrict__ cnt) {
    int idx  = blockIdx.x * 256 + threadIdx.x;   // 0..262143
    if (idx == 0) *cnt = 0;
    int j    = idx & 7;
    int lane = (idx >> 3) & 63;
    int nf   = (idx >> 9) & 3;
    int kf   = (idx >> 11) & 63;
    int term = idx >> 17;                        // 0..1
    int e = nf * 16 + (lane & 15);
    int d = kf * 32 + (lane >> 4) * 8 + j;
    float w = W[e * DIM + d];
    unsigned short h  = bf16_rne(w);
    float r1 = w - bf16_up(h);
    unsigned short md = bf16_rne(r1);
    warr[idx] = (short)((term == 0) ? h : md);
}

__device__ __forceinline__ bool gtie(float a, int ia, float b, int ib) {
    return (a > b) || (a == b && ia < ib);
}

// ---------------------------------------------------------------------------
// Kernel A: MFMA 2-way-split logits (err ~4e-6 vs np). Wave = 16 tokens x
// 64 experts (1 m-frag x 4 n-frags, 16x16x32 bf16, 4 split terms).
// Writes scores + top-2 idx/scores; flags tokens with top-margin < TAU.
// ---------------------------------------------------------------------------
__global__ __launch_bounds__(256, 2) void router_mfma(
        const float* __restrict__ X, const short* __restrict__ Wsp,
        const float* __restrict__ bias, float* __restrict__ out,
        int* __restrict__ cnt, int* __restrict__ list) {
    const int lane = threadIdx.x & 63;
    const int wid  = threadIdx.x >> 6;
    const int gw   = blockIdx.x * 4 + wid;     // 0..2047
    const int tok0 = gw * 16;
    const int l15  = lane & 15;
    const int l4   = lane >> 4;

    const float* xr = X + (size_t)(tok0 + l15) * DIM + l4 * 8;
    const short8* wp = (const short8*)Wsp + lane;  // + ((t*KF+kf)*4+n)*64

    f32x4 acc[4];
#pragma unroll
    for (int n = 0; n < 4; n++) acc[n] = (f32x4)0.0f;

    f32x4  a_cur[2];
    short8 b_cur[2][4];
    a_cur[0] = *(const f32x4*)(xr);
    a_cur[1] = *(const f32x4*)(xr + 4);
#pragma unroll
    for (int t = 0; t < 2; t++)
#pragma unroll
        for (int n = 0; n < 4; n++)
            b_cur[t][n] = wp[((t * KF + 0) * 4 + n) * 64];

    for (int kf = 0; kf < KF; ++kf) {
        const int kn = (kf + 1 < KF) ? kf + 1 : KF - 1;
        f32x4  a_nxt[2];
        short8 b_nxt[2][4];
        a_nxt[0] = *(const f32x4*)(xr + kn * 32);
        a_nxt[1] = *(const f32x4*)(xr + kn * 32 + 4);
#pragma unroll
        for (int t = 0; t < 2; t++)
#pragma unroll
            for (int n = 0; n < 4; n++)
                b_nxt[t][n] = wp[((t * KF + kn) * 4 + n) * 64];

        // 2-way bf16 split of A (8 elems)
        short8 ah, am;
#pragma unroll
        for (int j = 0; j < 8; j++) {
            float v = a_cur[j >> 2][j & 3];
            unsigned short h  = bf16_rne(v);
            float r1 = v - bf16_up(h);
            unsigned short md = bf16_rne(r1);
            ah[j] = (short)h;
            am[j] = (short)md;
        }

#pragma unroll
        for (int n = 0; n < 4; n++) {
            f32x4 c = acc[n];
            c = __builtin_amdgcn_mfma_f32_16x16x32_bf16(ah, b_cur[0][n], c, 0, 0, 0);
            c = __builtin_amdgcn_mfma_f32_16x16x32_bf16(ah, b_cur[1][n], c, 0, 0, 0);
            c = __builtin_amdgcn_mfma_f32_16x16x32_bf16(am, b_cur[0][n], c, 0, 0, 0);
            c = __builtin_amdgcn_mfma_f32_16x16x32_bf16(am, b_cur[1][n], c, 0, 0, 0);
            acc[n] = c;
        }

        a_cur[0] = a_nxt[0]; a_cur[1] = a_nxt[1];
#pragma unroll
        for (int t = 0; t < 2; t++)
#pragma unroll
            for (int n = 0; n < 4; n++) b_cur[t][n] = b_nxt[t][n];
    }

    // ------------- epilogue: bias + softmax + top-3 + flag -----------------
    float bv[4];
#pragma unroll
    for (int n = 0; n < 4; n++) bv[n] = bias[n * 16 + l15];

#pragma unroll
    for (int r = 0; r < 4; r++) {
        const int t = tok0 + l4 * 4 + r;       // C row = (lane>>4)*4+reg
        float v[4];
#pragma unroll
        for (int n = 0; n < 4; n++) v[n] = acc[n][r] + bv[n];

        float mx = fmaxf(fmaxf(v[0], v[1]), fmaxf(v[2], v[3]));
#pragma unroll
        for (int s = 1; s < 16; s <<= 1) mx = fmaxf(mx, __shfl_xor(mx, s, 64));

        float p[4], den = 0.0f;
#pragma unroll
        for (int n = 0; n < 4; n++) { p[n] = __expf(v[n] - mx); den += p[n]; }
#pragma unroll
        for (int s = 1; s < 16; s <<= 1) den += __shfl_xor(den, s, 64);
        const float inv = 1.0f / den;
#pragma unroll
        for (int n = 0; n < 4; n++)
            out[(size_t)t * 64 + n * 16 + l15] = p[n] * inv;

        // local top-3 over this lane's 4 experts
        float v1 = -3.4e38f, v2 = -3.4e38f, v3 = -3.4e38f;
        int   i1 = 9999,     i2 = 9999,     i3 = 9999;
#pragma unroll
        for (int n = 0; n < 4; n++) {
            float vv = v[n]; int ii = n * 16 + l15;
            if (gtie(vv, ii, v1, i1))      { v3=v2;i3=i2; v2=v1;i2=i1; v1=vv;i1=ii; }
            else if (gtie(vv, ii, v2, i2)) { v3=v2;i3=i2; v2=vv;i2=ii; }
            else if (gtie(vv, ii, v3, i3)) { v3=vv;i3=ii; }
        }
        // butterfly merge across the token's 16 lanes
#pragma unroll
        for (int s = 1; s < 16; s <<= 1) {
            float ov1=__shfl_xor(v1,s,64), ov2=__shfl_xor(v2,s,64), ov3=__shfl_xor(v3,s,64);
            int   oi1=__shfl_xor(i1,s,64), oi2=__shfl_xor(i2,s,64), oi3=__shfl_xor(i3,s,64);
            bool a1 = gtie(v1,i1,ov1,oi1);
            float w1 = a1?v1:ov1;  int k1 = a1?i1:oi1;
            float x1 = a1?v2:ov2;  int xi1= a1?i2:oi2;   // winner's 2nd
            float x2 = a1?v3:ov3;  int xi2= a1?i3:oi3;   // winner's 3rd
            float y1 = a1?ov1:v1;  int yi1= a1?oi1:i1;   // loser's 1st
            float y2 = a1?ov2:v2;  int yi2= a1?oi2:i2;   // loser's 2nd
            bool a2 = gtie(x1,xi1,y1,yi1);
            float w2 = a2?x1:y1;   int k2 = a2?xi1:yi1;
            float w3; int k3;
            if (a2) { bool a3 = gtie(x2,xi2,y1,yi1); w3 = a3?x2:y1; k3 = a3?xi2:yi1; }
            else    { bool a3 = gtie(x1,xi1,y2,yi2); w3 = a3?x1:y2; k3 = a3?xi1:yi2; }
            v1=w1;i1=k1; v2=w2;i2=k2; v3=w3;i3=k3;
        }
        if (l15 == 0) {
            out[OFF_IDX + (size_t)t * 2 + 0] = (float)i1;
            out[OFF_IDX + (size_t)t * 2 + 1] = (float)i2;
            out[OFF_TSC + (size_t)t * 2 + 0] = __expf(v1 - mx) * inv;
            out[OFF_TSC + (size_t)t * 2 + 1] = __expf(v2 - mx) * inv;
            if ((v1 - v2 < TAU) || (v2 - v3 < TAU)) {
                int slot = atomicAdd(cnt, 1);
                list[slot] = t;
            }
        }
    }
}

// ---------------------------------------------------------------------------
// Kernel B: exact np-chain recompute for flagged tokens (R3-R7 verified
// arithmetic): logit[t][e] = sequential fmaf over d=0..2047 asc, then +b[e].
// One block per token; wave 0 computes (lane=expert), LDS-staged W (double
// buffer, XOR-swizzled b128 rows), X row staged once.
// ---------------------------------------------------------------------------
__global__ __launch_bounds__(256, 2) void router_exact(
        const float* __restrict__ X, const float* __restrict__ W,
        const float* __restrict__ Bb, float* __restrict__ out,
        const int* __restrict__ cnt, const int* __restrict__ list) {
    __shared__ float xrow[2048];
    __shared__ char  wbuf[2][64 * 272] __attribute__((aligned(16)));
    const int tid = threadIdx.x;
    const int n   = *cnt;

    for (int ii = blockIdx.x; ii < n; ii += gridDim.x) {
        const int t = list[ii];
        // stage X row (8 KB) coalesced
#pragma unroll
        for (int q = 0; q < 2; ++q) {
            int s = tid + q * 256;               // 0..511 quads
            *(f32x4*)&xrow[s * 4] = *(const f32x4*)(X + (size_t)t * DIM + s * 4);
        }
        // stage W chunk 0 -> buf 0
#pragma unroll
        for (int q = 0; q < 4; ++q) {
            int s = tid + q * 256;               // 0..1023: e = s>>4, dq = s&15
            int e = s >> 4, dq = s & 15;
            f32x4 wv = *(const f32x4*)(W + (size_t)e * DIM + dq * 4);
            *(f32x4*)(wbuf[0] + e * 272 + ((16 * dq) ^ ((e & 7) << 4))) = wv;
        }
        __syncthreads();

        float acc = 0.0f;
#pragma unroll 1
        for (int c = 0; c < 32; ++c) {
            if (c + 1 < 32) {                    // stage next chunk -> buf^1
#pragma unroll
                for (int q = 0; q < 4; ++q) {
                    int s = tid + q * 256;
                    int e = s >> 4, dq = s & 15;
                    f32x4 wv = *(const f32x4*)(W + (size_t)e * DIM + (c + 1) * 64 + dq * 4);
                    *(f32x4*)(wbuf[(c + 1) & 1] + e * 272 + ((16 * dq) ^ ((e & 7) << 4))) = wv;
                }
            }
            if (tid < 64) {                      // wave 0: exact chain
                const char* wb = wbuf[c & 1] + tid * 272;
                const int sw = (tid & 7) << 4;
#pragma unroll
                for (int dq = 0; dq < 16; ++dq) {
                    f32x4 xq = *(const f32x4*)&xrow[c * 64 + dq * 4];
                    f32x4 wv = *(const f32x4*)(wb + ((16 * dq) ^ sw));
#pragma unroll
                    for (int j = 0; j < 4; ++j)
                        acc = fmaf(xq[j], wv[j], acc);   // strict ascending d
                }
            }
            __syncthreads();
        }

        if (tid < 64) {                          // wave 0 epilogue (R7-verified)
            const int lane = tid;
            const float lg = acc + Bb[lane];
            float m = lg;
#pragma unroll
            for (int s = 1; s < 64; s <<= 1) m = fmaxf(m, __shfl_xor(m, s, 64));
            const float p = __expf(lg - m);
            float den = p;
#pragma unroll
            for (int s = 1; s < 64; s <<= 1) den += __shfl_xor(den, s, 64);
            const float inv = 1.0f / den;
            out[(size_t)t * 64 + lane] = p * inv;

            float v1 = lg, v2 = -3.4e38f;
            int   i1 = lane, i2 = 127;
#pragma unroll
            for (int s = 1; s < 64; s <<= 1) {
                float ov1 = __shfl_xor(v1, s, 64), ov2 = __shfl_xor(v2, s, 64);
                int   oi1 = __shfl_xor(i1, s, 64), oi2 = __shfl_xor(i2, s, 64);
                bool  aw  = gtie(v1, i1, ov1, oi1);
                float nv1 = aw ? v1 : ov1;  int ni1 = aw ? i1 : oi1;
                float cv  = aw ? ov1 : v1;  int ci  = aw ? oi1 : i1;
                float sv  = aw ? v2 : ov2;  int si  = aw ? i2 : oi2;
                bool  c2  = gtie(cv, ci, sv, si);
                v1 = nv1; i1 = ni1;
                v2 = c2 ? cv : sv; i2 = c2 ? ci : si;
            }
            if (lane == 0) {
                out[OFF_IDX + (size_t)t * 2 + 0] = (float)i1;
                out[OFF_IDX + (size_t)t * 2 + 1] = (float)i2;
                out[OFF_TSC + (size_t)t * 2 + 0] = __expf(v1 - m) * inv;
                out[OFF_TSC + (size_t)t * 2 + 1] = __expf(v2 - m) * inv;
            }
        }
        __syncthreads();
    }
}

extern "C" void kernel_launch(void* const* d_in, const int* in_sizes, int n_in,
                              void* d_out, int out_size, void* d_ws, size_t ws_size,
                              hipStream_t stream) {
    const float* X = (const float*)d_in[0];   // [4,8192,2048] f32
    const float* W = (const float*)d_in[1];   // [64,2048] f32
    const float* b = (const float*)d_in[2];   // [64] f32
    float* out  = (float*)d_out;
    short* Wsp  = (short*)d_ws;                       // 512 KB
    int*   cnt  = (int*)((char*)d_ws + 524288);       // 4 B
    int*   list = (int*)((char*)d_ws + 524292);       // up to 128 KB

    wsplit<<<1024, 256, 0, stream>>>(W, Wsp, cnt);
    router_mfma<<<NTOK / 64, 256, 0, stream>>>(X, Wsp, b, out, cnt, list);
    router_exact<<<512, 256, 0, stream>>>(X, W, b, out, cnt, list);
}

// Round 9
// 124.038 us; speedup vs baseline: 5.6040x; 1.0419x over previous
//
#include <hip/hip_runtime.h>
#include <hip/hip_bf16.h>
#include <stdint.h>
#include <stddef.h>

#define DIM   2048
#define NEXP  64
#define NTOK  32768
#define KF    64                       // 2048/32 k-fragments
#define OFF_IDX  (NTOK*NEXP)           // 2097152
#define OFF_TSC  (OFF_IDX + NTOK*2)    // 2162688
#define TAU   5e-4f

typedef __attribute__((ext_vector_type(8))) short  short8;
typedef __attribute__((ext_vector_type(4))) float  f32x4;

__device__ __forceinline__ unsigned short bf16_rne(float f) {
    unsigned u = __builtin_bit_cast(unsigned, f);
    u += 0x7fffu + ((u >> 16) & 1u);
    return (unsigned short)(u >> 16);
}
__device__ __forceinline__ float bf16_up(unsigned short s) {
    unsigned u = ((unsigned)s) << 16;
    return __builtin_bit_cast(float, u);
}

// ---------------------------------------------------------------------------
// Pre-kernel: split W into 2 bf16 terms (hi/mid) in MFMA B-fragment order.
// short idx = ((((term*KF+kf)*4+nf)*64)+lane)*8 + j  (262144 shorts = 512KB)
// Also zeroes the ambiguous-token counter (runs before router_mfma).
// ---------------------------------------------------------------------------
__global__ __launch_bounds__(256) void wsplit(const float* __restrict__ W,
                                              short* __restrict__ warr,
                                              int* __restrict__ cnt) {
    int idx  = blockIdx.x * 256 + threadIdx.x;   // 0..262143
    if (idx == 0) *cnt = 0;
    int j    = idx & 7;
    int lane = (idx >> 3) & 63;
    int nf   = (idx >> 9) & 3;
    int kf   = (idx >> 11) & 63;
    int term = idx >> 17;                        // 0..1
    int e = nf * 16 + (lane & 15);
    int d = kf * 32 + (lane >> 4) * 8 + j;
    float w = W[e * DIM + d];
    unsigned short h  = bf16_rne(w);
    float r1 = w - bf16_up(h);
    unsigned short md = bf16_rne(r1);
    warr[idx] = (short)((term == 0) ? h : md);
}

__device__ __forceinline__ bool gtie(float a, int ia, float b, int ib) {
    return (a > b) || (a == b && ia < ib);
}

// ---------------------------------------------------------------------------
// Kernel A: MFMA 2-way-split logits (err ~4e-6 vs np). Wave = 16 tokens x
// 64 experts. R9: A-prefetch ring 4 kf deep (static indices via full
// 4-phase unroll), B double-buffer 1 deep (L1-hot). Flags margin < TAU.
// ---------------------------------------------------------------------------
__global__ __launch_bounds__(256, 2) void router_mfma(
        const float* __restrict__ X, const short* __restrict__ Wsp,
        const float* __restrict__ bias, float* __restrict__ out,
        int* __restrict__ cnt, int* __restrict__ list) {
    const int lane = threadIdx.x & 63;
    const int wid  = threadIdx.x >> 6;
    const int gw   = blockIdx.x * 4 + wid;     // 0..2047
    const int tok0 = gw * 16;
    const int l15  = lane & 15;
    const int l4   = lane >> 4;

    const float* xr = X + (size_t)(tok0 + l15) * DIM + l4 * 8;
    const short8* wp = (const short8*)Wsp + lane;  // + ((t*KF+kf)*4+n)*64

    f32x4 acc[4];
#pragma unroll
    for (int n = 0; n < 4; n++) acc[n] = (f32x4)0.0f;

    // 4-deep A prefetch ring (indices static after unroll), 1-deep B dbuf
    f32x4  a_pf[4][2];
    short8 b_pf[2][2][4];
#pragma unroll
    for (int p = 0; p < 4; p++) {
        a_pf[p][0] = *(const f32x4*)(xr + p * 32);
        a_pf[p][1] = *(const f32x4*)(xr + p * 32 + 4);
    }
#pragma unroll
    for (int t = 0; t < 2; t++)
#pragma unroll
        for (int n = 0; n < 4; n++)
            b_pf[0][t][n] = wp[((t * KF + 0) * 4 + n) * 64];

#pragma unroll 1
    for (int base = 0; base < KF; base += 4) {
#pragma unroll
        for (int p = 0; p < 4; ++p) {
            const int kf  = base + p;
            const int kn1 = (kf + 1 < KF) ? kf + 1 : KF - 1;
            const int kn4 = (kf + 4 < KF) ? kf + 4 : KF - 1;

            // B prefetch for kf+1 into the other buffer
#pragma unroll
            for (int t = 0; t < 2; t++)
#pragma unroll
                for (int n = 0; n < 4; n++)
                    b_pf[(p + 1) & 1][t][n] = wp[((t * KF + kn1) * 4 + n) * 64];

            // take current A, immediately reissue its slot for kf+4
            f32x4 a0 = a_pf[p][0], a1 = a_pf[p][1];
            a_pf[p][0] = *(const f32x4*)(xr + kn4 * 32);
            a_pf[p][1] = *(const f32x4*)(xr + kn4 * 32 + 4);

            // 2-way bf16 split of A (8 elems)
            short8 ah, am;
#pragma unroll
            for (int j = 0; j < 8; j++) {
                float v = (j < 4) ? a0[j & 3] : a1[j & 3];
                unsigned short h  = bf16_rne(v);
                float r1 = v - bf16_up(h);
                unsigned short md = bf16_rne(r1);
                ah[j] = (short)h;
                am[j] = (short)md;
            }

#pragma unroll
            for (int n = 0; n < 4; n++) {
                f32x4 c = acc[n];
                c = __builtin_amdgcn_mfma_f32_16x16x32_bf16(ah, b_pf[p & 1][0][n], c, 0, 0, 0);
                c = __builtin_amdgcn_mfma_f32_16x16x32_bf16(ah, b_pf[p & 1][1][n], c, 0, 0, 0);
                c = __builtin_amdgcn_mfma_f32_16x16x32_bf16(am, b_pf[p & 1][0][n], c, 0, 0, 0);
                c = __builtin_amdgcn_mfma_f32_16x16x32_bf16(am, b_pf[p & 1][1][n], c, 0, 0, 0);
                acc[n] = c;
            }
        }
    }

    // ------------- epilogue: bias + softmax + top-3 + flag -----------------
    float bv[4];
#pragma unroll
    for (int n = 0; n < 4; n++) bv[n] = bias[n * 16 + l15];

#pragma unroll
    for (int r = 0; r < 4; r++) {
        const int t = tok0 + l4 * 4 + r;       // C row = (lane>>4)*4+reg
        float v[4];
#pragma unroll
        for (int n = 0; n < 4; n++) v[n] = acc[n][r] + bv[n];

        float mx = fmaxf(fmaxf(v[0], v[1]), fmaxf(v[2], v[3]));
#pragma unroll
        for (int s = 1; s < 16; s <<= 1) mx = fmaxf(mx, __shfl_xor(mx, s, 64));

        float p[4], den = 0.0f;
#pragma unroll
        for (int n = 0; n < 4; n++) { p[n] = __expf(v[n] - mx); den += p[n]; }
#pragma unroll
        for (int s = 1; s < 16; s <<= 1) den += __shfl_xor(den, s, 64);
        const float inv = 1.0f / den;
#pragma unroll
        for (int n = 0; n < 4; n++)
            out[(size_t)t * 64 + n * 16 + l15] = p[n] * inv;

        // local top-3 over this lane's 4 experts
        float v1 = -3.4e38f, v2 = -3.4e38f, v3 = -3.4e38f;
        int   i1 = 9999,     i2 = 9999,     i3 = 9999;
#pragma unroll
        for (int n = 0; n < 4; n++) {
            float vv = v[n]; int ii = n * 16 + l15;
            if (gtie(vv, ii, v1, i1))      { v3=v2;i3=i2; v2=v1;i2=i1; v1=vv;i1=ii; }
            else if (gtie(vv, ii, v2, i2)) { v3=v2;i3=i2; v2=vv;i2=ii; }
            else if (gtie(vv, ii, v3, i3)) { v3=vv;i3=ii; }
        }
        // butterfly merge across the token's 16 lanes
#pragma unroll
        for (int s = 1; s < 16; s <<= 1) {
            float ov1=__shfl_xor(v1,s,64), ov2=__shfl_xor(v2,s,64), ov3=__shfl_xor(v3,s,64);
            int   oi1=__shfl_xor(i1,s,64), oi2=__shfl_xor(i2,s,64), oi3=__shfl_xor(i3,s,64);
            bool a1 = gtie(v1,i1,ov1,oi1);
            float w1 = a1?v1:ov1;  int k1 = a1?i1:oi1;
            float x1 = a1?v2:ov2;  int xi1= a1?i2:oi2;   // winner's 2nd
            float x2 = a1?v3:ov3;  int xi2= a1?i3:oi3;   // winner's 3rd
            float y1 = a1?ov1:v1;  int yi1= a1?oi1:i1;   // loser's 1st
            float y2 = a1?ov2:v2;  int yi2= a1?oi2:i2;   // loser's 2nd
            bool a2 = gtie(x1,xi1,y1,yi1);
            float w2 = a2?x1:y1;   int k2 = a2?xi1:yi1;
            float w3; int k3;
            if (a2) { bool a3 = gtie(x2,xi2,y1,yi1); w3 = a3?x2:y1; k3 = a3?xi2:yi1; }
            else    { bool a3 = gtie(x1,xi1,y2,yi2); w3 = a3?x1:y2; k3 = a3?xi1:yi2; }
            v1=w1;i1=k1; v2=w2;i2=k2; v3=w3;i3=k3;
        }
        if (l15 == 0) {
            out[OFF_IDX + (size_t)t * 2 + 0] = (float)i1;
            out[OFF_IDX + (size_t)t * 2 + 1] = (float)i2;
            out[OFF_TSC + (size_t)t * 2 + 0] = __expf(v1 - mx) * inv;
            out[OFF_TSC + (size_t)t * 2 + 1] = __expf(v2 - mx) * inv;
            if ((v1 - v2 < TAU) || (v2 - v3 < TAU)) {
                int slot = atomicAdd(cnt, 1);
                list[slot] = t;
            }
        }
    }
}

// ---------------------------------------------------------------------------
// Kernel B: exact np-chain recompute for flagged tokens (R3-R8 verified
// arithmetic): logit[t][e] = sequential fmaf over d=0..2047 asc, then +b[e].
// ---------------------------------------------------------------------------
__global__ __launch_bounds__(256, 2) void router_exact(
        const float* __restrict__ X, const float* __restrict__ W,
        const float* __restrict__ Bb, float* __restrict__ out,
        const int* __restrict__ cnt, const int* __restrict__ list) {
    __shared__ float xrow[2048];
    __shared__ char  wbuf[2][64 * 272] __attribute__((aligned(16)));
    const int tid = threadIdx.x;
    const int n   = *cnt;

    for (int ii = blockIdx.x; ii < n; ii += gridDim.x) {
        const int t = list[ii];
#pragma unroll
        for (int q = 0; q < 2; ++q) {
            int s = tid + q * 256;               // 0..511 quads
            *(f32x4*)&xrow[s * 4] = *(const f32x4*)(X + (size_t)t * DIM + s * 4);
        }
#pragma unroll
        for (int q = 0; q < 4; ++q) {
            int s = tid + q * 256;               // 0..1023: e = s>>4, dq = s&15
            int e = s >> 4, dq = s & 15;
            f32x4 wv = *(const f32x4*)(W + (size_t)e * DIM + dq * 4);
            *(f32x4*)(wbuf[0] + e * 272 + ((16 * dq) ^ ((e & 7) << 4))) = wv;
        }
        __syncthreads();

        float acc = 0.0f;
#pragma unroll 1
        for (int c = 0; c < 32; ++c) {
            if (c + 1 < 32) {
#pragma unroll
                for (int q = 0; q < 4; ++q) {
                    int s = tid + q * 256;
                    int e = s >> 4, dq = s & 15;
                    f32x4 wv = *(const f32x4*)(W + (size_t)e * DIM + (c + 1) * 64 + dq * 4);
                    *(f32x4*)(wbuf[(c + 1) & 1] + e * 272 + ((16 * dq) ^ ((e & 7) << 4))) = wv;
                }
            }
            if (tid < 64) {
                const char* wb = wbuf[c & 1] + tid * 272;
                const int sw = (tid & 7) << 4;
#pragma unroll
                for (int dq = 0; dq < 16; ++dq) {
                    f32x4 xq = *(const f32x4*)&xrow[c * 64 + dq * 4];
                    f32x4 wv = *(const f32x4*)(wb + ((16 * dq) ^ sw));
#pragma unroll
                    for (int j = 0; j < 4; ++j)
                        acc = fmaf(xq[j], wv[j], acc);   // strict ascending d
                }
            }
            __syncthreads();
        }

        if (tid < 64) {
            const int lane = tid;
            const float lg = acc + Bb[lane];
            float m = lg;
#pragma unroll
            for (int s = 1; s < 64; s <<= 1) m = fmaxf(m, __shfl_xor(m, s, 64));
            const float p = __expf(lg - m);
            float den = p;
#pragma unroll
            for (int s = 1; s < 64; s <<= 1) den += __shfl_xor(den, s, 64);
            const float inv = 1.0f / den;
            out[(size_t)t * 64 + lane] = p * inv;

            float v1 = lg, v2 = -3.4e38f;
            int   i1 = lane, i2 = 127;
#pragma unroll
            for (int s = 1; s < 64; s <<= 1) {
                float ov1 = __shfl_xor(v1, s, 64), ov2 = __shfl_xor(v2, s, 64);
                int   oi1 = __shfl_xor(i1, s, 64), oi2 = __shfl_xor(i2, s, 64);
                bool  aw  = gtie(v1, i1, ov1, oi1);
                float nv1 = aw ? v1 : ov1;  int ni1 = aw ? i1 : oi1;
                float cv  = aw ? ov1 : v1;  int ci  = aw ? oi1 : i1;
                float sv  = aw ? v2 : ov2;  int si  = aw ? i2 : oi2;
                bool  c2  = gtie(cv, ci, sv, si);
                v1 = nv1; i1 = ni1;
                v2 = c2 ? cv : sv; i2 = c2 ? ci : si;
            }
            if (lane == 0) {
                out[OFF_IDX + (size_t)t * 2 + 0] = (float)i1;
                out[OFF_IDX + (size_t)t * 2 + 1] = (float)i2;
                out[OFF_TSC + (size_t)t * 2 + 0] = __expf(v1 - m) * inv;
                out[OFF_TSC + (size_t)t * 2 + 1] = __expf(v2 - m) * inv;
            }
        }
        __syncthreads();
    }
}

extern "C" void kernel_launch(void* const* d_in, const int* in_sizes, int n_in,
                              void* d_out, int out_size, void* d_ws, size_t ws_size,
                              hipStream_t stream) {
    const float* X = (const float*)d_in[0];   // [4,8192,2048] f32
    const float* W = (const float*)d_in[1];   // [64,2048] f32
    const float* b = (const float*)d_in[2];   // [64] f32
    float* out  = (float*)d_out;
    short* Wsp  = (short*)d_ws;                       // 512 KB
    int*   cnt  = (int*)((char*)d_ws + 524288);       // 4 B
    int*   list = (int*)((char*)d_ws + 524292);       // up to 128 KB

    wsplit<<<1024, 256, 0, stream>>>(W, Wsp, cnt);
    router_mfma<<<NTOK / 64, 256, 0, stream>>>(X, Wsp, b, out, cnt, list);
    router_exact<<<512, 256, 0, stream>>>(X, W, b, out, cnt, list);
}